// Round 14
// baseline (163.030 us; speedup 1.0000x reference)
//
#include <hip/hip_runtime.h>
#include <hip/hip_bf16.h>

#define DD 64
#define ECH 64      // edges per chunk
#define NEB 512     // edgesum blocks (2 per CU -- the point of this round)
#define GB 256      // graph bins (B==256)
#define MAXPER 1600 // >= ceil(E/NEB)=1563

typedef __attribute__((ext_vector_type(8))) short bf16x8_t;
typedef __attribute__((ext_vector_type(4))) float f32x4_t;

__device__ __forceinline__ ushort f2b(float x) {
  __hip_bfloat16 h = __float2bfloat16(x);
  ushort r;
  __builtin_memcpy(&r, &h, 2);
  return r;
}

// XOR swizzle for 128B-row LDS tiles: h = (row&7) ^ ((row>>3)&7), byte ^= h<<4.
//  * fragment reads (16 consecutive rows): h covers all 8 values twice -> 2-way
//  * Vt transpose writes (rows d0..d0+3 per thread, col p=tid&31 spans all 32
//    banks): permutation within each half -> 2-way
__device__ __forceinline__ uint swz128(uint b) {
  return b ^ (((((b >> 7) & 7u)) ^ ((b >> 10) & 7u)) << 4);
}

__global__ __launch_bounds__(256) void k_zero(int* __restrict__ p, int n) {
  int gid = blockIdx.x * blockDim.x + threadIdx.x;
  int stride = gridDim.x * blockDim.x;
  for (int i = gid; i < n; i += stride) p[i] = 0;
}

__global__ __launch_bounds__(256) void k_hist(const int* __restrict__ eidx,
                                              int* __restrict__ cnt, int E) {
  int gid = blockIdx.x * blockDim.x + threadIdx.x;
  int stride = gridDim.x * blockDim.x;
  int E4 = E >> 2;
  const int4* e4 = reinterpret_cast<const int4*>(eidx);
  for (int i = gid; i < E4; i += stride) {
    int4 v = e4[i];
    atomicAdd(&cnt[v.x], 1);
    atomicAdd(&cnt[v.y], 1);
    atomicAdd(&cnt[v.z], 1);
    atomicAdd(&cnt[v.w], 1);
  }
  for (int e = (E4 << 2) + gid; e < E; e += stride) atomicAdd(&cnt[eidx[e]], 1);
}

// ---------------------------------------------------------------------------
// Edge -> graph-bin accumulation as one-hot GEMM (R12/R13 structure).
// R14 delta: ECH 128->64 shrinks LDS to 52.8KB -> 2 blocks/CU. The co-resident
// block's waves fill the lgkm/barrier/phase-transition bubbles that dominated
// at 1 block/CU (R13: 6720 cyc/chunk vs ~3400 resource cycles).
//   S[256 bins][64 k]  bf16, 128B rows, swizzled   32 KB
//   Vt[64 dims][64 k]  bf16, 128B rows, swizzled    8 KB
//   meta int2[1600]                                12.8 KB
// ---------------------------------------------------------------------------
__global__ __launch_bounds__(512, 4) void k_edgesum(const float* __restrict__ edge_attr,
                                                    const int* __restrict__ eidx,
                                                    const int* __restrict__ cnt,
                                                    const int* __restrict__ batch,
                                                    float* __restrict__ partial, int E) {
  __shared__ ushort S[256 * 64];  // 32 KB
  __shared__ ushort Vt[64 * 64];  // 8 KB
  __shared__ int2 meta[MAXPER];   // 12.8 KB
  const int tid = threadIdx.x;
  const int lane = tid & 63, wv = tid >> 6;
  const int r15 = lane & 15, kq = lane >> 4;
  const int m0 = wv * 32;  // this wave's 32 bins

  const int per = (E + NEB - 1) / NEB;  // 1563
  const int base = blockIdx.x * per;
  const int nE = max(0, min(per, E - base));
  const int nch = (nE + ECH - 1) / ECH;

  const int p = tid & 31;         // edge pair (e = 2p, 2p+1)
  const int d0 = (tid >> 5) * 4;  // dims d0..d0+3

  float4 rA[2], rB[2];  // [0]: edge 2p dims d0..+3, [1]: edge 2p+1

#define LOADC(c, R)                                                              \
  do {                                                                           \
    size_t r0_ = (size_t)min(base + (c)*ECH + 2 * p, E - 1);                     \
    size_t r1_ = (size_t)min(base + (c)*ECH + 2 * p + 1, E - 1);                 \
    R[0] = *reinterpret_cast<const float4*>(edge_attr + r0_ * DD + d0);          \
    R[1] = *reinterpret_cast<const float4*>(edge_attr + r1_ * DD + d0);          \
  } while (0)

#define PHASEW(c, R)                                                             \
  do {                                                                           \
    _Pragma("unroll") for (int j = 0; j < 4; ++j) {                              \
      uint w32_ = (uint)f2b(((const float*)&R[0])[j]) |                          \
                  ((uint)f2b(((const float*)&R[1])[j]) << 16);                   \
      *(uint*)((char*)Vt + swz128(((uint)(d0 + j)) * 128 + (uint)p * 4)) = w32_; \
    }                                                                            \
    if (tid < ECH) {                                                             \
      if (prev >= 0) *(ushort*)((char*)S + swz128((uint)prev * 128 + tid * 2)) = 0; \
      int2 mm_ = meta[(c)*ECH + tid];                                            \
      if (mm_.x >= 0) {                                                          \
        *(ushort*)((char*)S + swz128((uint)mm_.x * 128 + tid * 2)) =             \
            f2b(__int_as_float(mm_.y));                                          \
        prev = mm_.x;                                                            \
      } else {                                                                   \
        prev = -1;                                                               \
      }                                                                          \
    }                                                                            \
  } while (0)

#define MFMAP()                                                                  \
  do {                                                                           \
    _Pragma("unroll") for (int ks = 0; ks < 2; ++ks) {                           \
      uint ko_ = (uint)(ks * 64 + kq * 16);                                      \
      bf16x8_t b0_ = *(const bf16x8_t*)((const char*)Vt + swz128((uint)(r15)*128 + ko_)); \
      bf16x8_t b1_ = *(const bf16x8_t*)((const char*)Vt +                        \
                                        swz128((uint)(16 + r15) * 128 + ko_));   \
      bf16x8_t b2_ = *(const bf16x8_t*)((const char*)Vt +                        \
                                        swz128((uint)(32 + r15) * 128 + ko_));   \
      bf16x8_t b3_ = *(const bf16x8_t*)((const char*)Vt +                        \
                                        swz128((uint)(48 + r15) * 128 + ko_));   \
      _Pragma("unroll") for (int mt = 0; mt < 2; ++mt) {                         \
        bf16x8_t a_ = *(const bf16x8_t*)((const char*)S +                        \
                                         swz128((uint)(m0 + mt * 16 + r15) * 128 + ko_)); \
        acc[mt][0] = __builtin_amdgcn_mfma_f32_16x16x32_bf16(a_, b0_, acc[mt][0], 0, 0, 0); \
        acc[mt][1] = __builtin_amdgcn_mfma_f32_16x16x32_bf16(a_, b1_, acc[mt][1], 0, 0, 0); \
        acc[mt][2] = __builtin_amdgcn_mfma_f32_16x16x32_bf16(a_, b2_, acc[mt][2], 0, 0, 0); \
        acc[mt][3] = __builtin_amdgcn_mfma_f32_16x16x32_bf16(a_, b3_, acc[mt][3], 0, 0, 0); \
      }                                                                          \
    }                                                                            \
  } while (0)

#define LGKM0() asm volatile("s_waitcnt lgkmcnt(0)" ::: "memory")

  f32x4_t acc[2][4];
#pragma unroll
  for (int a = 0; a < 2; ++a)
#pragma unroll
    for (int nt = 0; nt < 4; ++nt) acc[a][nt] = (f32x4_t)(0.0f);

  // prologue: fire chunk 0/1 loads early, then S zero + meta precompute
  if (nch > 0) LOADC(0, rA);
  if (nch > 1) LOADC(1, rB);
  for (int i = tid; i < 256 * 64 / 2; i += 512) ((uint*)S)[i] = 0u;
  for (int i = tid; i < MAXPER; i += 512) {
    int pb = -1;
    float pw = 0.f;
    if (i < nE) {
      int n = eidx[base + i];
      pw = 1.0f / fmaxf((float)cnt[n], 1.0f);
      pb = batch[n];
    }
    meta[i] = make_int2(pb, __float_as_int(pw));
  }
  int prev = -1;
  __syncthreads();

  for (int c = 0; c < nch; c += 2) {
    PHASEW(c, rA);
    LGKM0();
    __builtin_amdgcn_s_barrier();
    if (c + 2 < nch) LOADC(c + 2, rA);
    MFMAP();
    LGKM0();
    __builtin_amdgcn_s_barrier();
    if (c + 1 < nch) {
      PHASEW(c + 1, rB);
      LGKM0();
      __builtin_amdgcn_s_barrier();
      if (c + 3 < nch) LOADC(c + 3, rB);
      MFMAP();
      LGKM0();
      __builtin_amdgcn_s_barrier();
    }
  }

  // epilogue: acc -> partial[blk][bin][d] (contiguous 64KB per block)
  // D layout (16x16x32): col = lane&15, row = (lane>>4)*4 + j  [m89]
  float* outp = partial + (size_t)blockIdx.x * GB * DD;
#pragma unroll
  for (int mt = 0; mt < 2; ++mt)
#pragma unroll
    for (int nt = 0; nt < 4; ++nt)
#pragma unroll
      for (int j = 0; j < 4; ++j) {
        int row = m0 + mt * 16 + kq * 4 + j;
        int col = nt * 16 + r15;
        outp[row * DD + col] = acc[mt][nt][j];
      }
#undef LOADC
#undef PHASEW
#undef MFMAP
#undef LGKM0
}

// ---------------------------------------------------------------------------
// Per-graph: reduce NEB partials + pool x + copy u -> bf16 comb row.
// ---------------------------------------------------------------------------
__global__ __launch_bounds__(256) void k_reduce(const float* __restrict__ partial,
                                                const float* __restrict__ x,
                                                const float* __restrict__ u,
                                                const int* __restrict__ batch,
                                                ushort* __restrict__ comb, int N) {
  __shared__ int s_lo, s_hi;
  __shared__ float rE[4][64], rV[4][64];
  int b = blockIdx.x;
  int tid = threadIdx.x;
  if (tid == 0) {
    int lo = 0, hi = N;
    while (lo < hi) { int m = (lo + hi) >> 1; if (batch[m] < b) lo = m + 1; else hi = m; }
    s_lo = lo;
    hi = N;
    while (lo < hi) { int m = (lo + hi) >> 1; if (batch[m] < b + 1) lo = m + 1; else hi = m; }
    s_hi = lo;
  }
  __syncthreads();
  int lo = s_lo, hi = s_hi;
  int d = tid & 63, sub = tid >> 6;
  float accE = 0.f, accV = 0.f;
  for (int p = sub; p < NEB; p += 4)
    accE += partial[((size_t)p * GB + b) * DD + d];
  for (int n = lo + sub; n < hi; n += 4)
    accV += x[(size_t)n * DD + d];
  rE[sub][d] = accE;
  rV[sub][d] = accV;
  __syncthreads();
  if (sub == 0) {
    float invNb = 1.0f / fmaxf((float)(hi - lo), 1.0f);
    float ue = (rE[0][d] + rE[1][d] + rE[2][d] + rE[3][d]) * invNb;
    float uv = (rV[0][d] + rV[1][d] + rV[2][d] + rV[3][d]) * invNb;
    ushort* row = comb + (size_t)b * 192;
    row[d] = f2b(ue);
    row[64 + d] = f2b(uv);
    row[128 + d] = f2b(u[(size_t)b * DD + d]);
  }
}

// ---------------------------------------------------------------------------
// MFMA MLP: 1 block, 512 threads (8 waves), all weights pre-staged behind one
// barrier. Proven (absmax 0.039 << 0.13).
// ---------------------------------------------------------------------------
template <int K, int WS, bool FIRST, bool LAST>
__device__ __forceinline__ void mlp_layer(int tid, const ushort* __restrict__ combg,
                                          float* hbuf, ushort* a_lds,
                                          const ushort* w_lds, const float* bias_s,
                                          float* ps, float* pq, float* ab, float* bb,
                                          const float* __restrict__ gamma,
                                          const float* __restrict__ beta,
                                          float* __restrict__ out) {
  const int lane = tid & 63, wv = tid >> 6;
  f32x4_t acc[2][4];
#pragma unroll
  for (int a = 0; a < 2; ++a)
#pragma unroll
    for (int nt = 0; nt < 4; ++nt) acc[a][nt] = (f32x4_t)(0.0f);

  const int m0 = wv * 32;
  const int r15 = lane & 15, kq = lane >> 4;
  for (int kk = 0; kk < K; kk += 32) {
    int koff = kk + kq * 8;
    bf16x8_t af[2], bf[4];
    if (FIRST) {
      const ushort* ap = combg + (size_t)(m0 + r15) * 192 + koff;
      af[0] = *reinterpret_cast<const bf16x8_t*>(ap);
      af[1] = *reinterpret_cast<const bf16x8_t*>(ap + 16 * 192);
    } else {
      const ushort* ap = &a_lds[(m0 + r15) * 72 + koff];
      af[0] = *reinterpret_cast<const bf16x8_t*>(ap);
      af[1] = *reinterpret_cast<const bf16x8_t*>(ap + 16 * 72);
    }
#pragma unroll
    for (int nt = 0; nt < 4; ++nt)
      bf[nt] = *reinterpret_cast<const bf16x8_t*>(&w_lds[(nt * 16 + r15) * WS + koff]);
#pragma unroll
    for (int a = 0; a < 2; ++a)
#pragma unroll
      for (int nt = 0; nt < 4; ++nt)
        acc[a][nt] = __builtin_amdgcn_mfma_f32_16x16x32_bf16(af[a], bf[nt], acc[a][nt], 0, 0, 0);
  }

#pragma unroll
  for (int a = 0; a < 2; ++a) {
#pragma unroll
    for (int nt = 0; nt < 4; ++nt) {
      int col = nt * 16 + r15;
#pragma unroll
      for (int j = 0; j < 4; ++j) {
        int row = m0 + a * 16 + kq * 4 + j;
        float v = acc[a][nt][j] + bias_s[col];
        hbuf[row * 65 + col] = fmaxf(v, 0.f);
      }
    }
  }
  __syncthreads();

  {
    int col = tid & 63, seg = tid >> 6;
    float s = 0.f, q = 0.f;
#pragma unroll
    for (int t = 0; t < 32; ++t) {
      float v = hbuf[(seg * 32 + t) * 65 + col];
      s += v;
      q += v * v;
    }
    ps[seg * 64 + col] = s;
    pq[seg * 64 + col] = q;
  }
  __syncthreads();
  if (tid < 64) {
    float s = 0.f, q = 0.f;
#pragma unroll
    for (int g = 0; g < 8; ++g) {
      s += ps[g * 64 + tid];
      q += pq[g * 64 + tid];
    }
    float mu = s * (1.0f / 256.0f);
    float var = q * (1.0f / 256.0f) - mu * mu;
    float rs = rsqrtf(var + 1e-5f);
    float A = gamma[tid] * rs;
    ab[tid] = A;
    bb[tid] = beta[tid] - mu * A;
  }
  __syncthreads();
  for (int i = tid; i < 256 * 64; i += 512) {
    int r = i >> 6, c = i & 63;
    float y = hbuf[r * 65 + c] * ab[c] + bb[c];
    if (LAST)
      out[i] = y;
    else
      a_lds[r * 72 + c] = f2b(y);
  }
  __syncthreads();
}

__global__ __launch_bounds__(512) void k_mlp(const ushort* __restrict__ comb,
                                             const float* W0, const float* b0,
                                             const float* W1, const float* b1,
                                             const float* W2, const float* b2,
                                             const float* g0, const float* be0,
                                             const float* g1, const float* be1,
                                             const float* g2, const float* be2,
                                             float* __restrict__ out) {
  __shared__ __align__(16) float hbuf[256 * 65];    // 66.6 KB
  __shared__ __align__(16) ushort a_lds[256 * 72];  // 36.9 KB
  __shared__ __align__(16) ushort w0s[64 * 200];    // 25.6 KB
  __shared__ __align__(16) ushort w1s[64 * 72];     // 9.2 KB
  __shared__ __align__(16) ushort w2s[64 * 72];     // 9.2 KB
  __shared__ float ps[8 * 64], pq[8 * 64];
  __shared__ float b0s[64], b1s[64], b2s[64], ab[64], bb[64];
  int tid = threadIdx.x;

  for (int i = tid; i < 64 * 192; i += 512) {
    int r = i / 192, c = i - r * 192;
    w0s[r * 200 + c] = f2b(W0[i]);
  }
  for (int i = tid; i < 64 * 64; i += 512) {
    int r = i >> 6, c = i & 63;
    w1s[r * 72 + c] = f2b(W1[i]);
    w2s[r * 72 + c] = f2b(W2[i]);
  }
  if (tid < 64) {
    b0s[tid] = b0[tid];
    b1s[tid] = b1[tid];
    b2s[tid] = b2[tid];
  }
  __syncthreads();

  mlp_layer<192, 200, true, false>(tid, comb, hbuf, a_lds, w0s, b0s, ps, pq, ab, bb,
                                   g0, be0, nullptr);
  mlp_layer<64, 72, false, false>(tid, comb, hbuf, a_lds, w1s, b1s, ps, pq, ab, bb,
                                  g1, be1, nullptr);
  mlp_layer<64, 72, false, true>(tid, comb, hbuf, a_lds, w2s, b2s, ps, pq, ab, bb,
                                 g2, be2, out);
}

extern "C" void kernel_launch(void* const* d_in, const int* in_sizes, int n_in,
                              void* d_out, int out_size, void* d_ws, size_t ws_size,
                              hipStream_t stream) {
  (void)n_in; (void)out_size; (void)ws_size;
  const float* x         = (const float*)d_in[0];
  const float* edge_attr = (const float*)d_in[1];
  const float* u         = (const float*)d_in[2];
  const int*   eidx      = (const int*)d_in[3];  // row 0 = first E entries
  const int*   batch     = (const int*)d_in[4];
  const float* W0 = (const float*)d_in[5];
  const float* b0 = (const float*)d_in[6];
  const float* W1 = (const float*)d_in[7];
  const float* b1 = (const float*)d_in[8];
  const float* W2 = (const float*)d_in[9];
  const float* b2 = (const float*)d_in[10];
  const float* g0 = (const float*)d_in[11];
  const float* be0 = (const float*)d_in[12];
  const float* g1 = (const float*)d_in[13];
  const float* be1 = (const float*)d_in[14];
  const float* g2 = (const float*)d_in[15];
  const float* be2 = (const float*)d_in[16];

  int N = in_sizes[0] / DD;
  int E = in_sizes[1] / DD;

  // ws layout (16B padded): partial[NEB*GB*64] f32 (33.5MB) | cnt[N] | comb
  float* partial = (float*)d_ws;
  int* cnt = (int*)(partial + (size_t)NEB * GB * DD);
  ushort* comb = (ushort*)(cnt + ((N + 3) & ~3));

  k_zero<<<64, 256, 0, stream>>>(cnt, N);
  k_hist<<<1024, 256, 0, stream>>>(eidx, cnt, E);
  k_edgesum<<<NEB, 512, 0, stream>>>(edge_attr, eidx, cnt, batch, partial, E);
  k_reduce<<<256, 256, 0, stream>>>(partial, x, u, batch, comb, N);
  k_mlp<<<1, 512, 0, stream>>>(comb, W0, b0, W1, b1, W2, b2,
                               g0, be0, g1, be1, g2, be2, (float*)d_out);
}